// Round 3
// baseline (3590.010 us; speedup 1.0000x reference)
//
#include <hip/hip_runtime.h>
#include <math.h>

#define BS 8192
#define HID 256
#define SPB1 16

// ---- workspace layout (float element offsets) ----
#define WT1_OFF 0
#define WT2_OFF 65536
#define WT3_OFF 131072
#define WT0_OFF 196608
#define S_OFF   204800
#define C_OFF   (S_OFF + 4 * BS * HID)
#define G_OFF   (C_OFF + 4 * BS * HID)
#define WBT_OFF (G_OFF + BS * 16)
// WBT region: 3 layers x 2 (hi,lo) x 256 x 256 ushort = 786432 B after WBT_OFF floats

typedef __attribute__((ext_vector_type(8))) short bf16x8;
typedef __attribute__((ext_vector_type(16))) float f32x16;
#define MFMA32(A, B, C) __builtin_amdgcn_mfma_f32_32x32x16_bf16(A, B, C, 0, 0, 0)

__device__ __forceinline__ ushort bf16_rne(float x) {
    unsigned u = __float_as_uint(x);
    unsigned r = u + 0x7FFFu + ((u >> 16) & 1u);
    return (ushort)(r >> 16);
}
__device__ __forceinline__ void bsplit(float x, ushort& hi, ushort& lo) {
    hi = bf16_rne(x);
    float hf = __uint_as_float(((unsigned)hi) << 16);
    lo = bf16_rne(x - hf);
}

__device__ __forceinline__ void silu_derivs(float a, float& h, float& sp, float& fpp) {
    float sig = 1.0f / (1.0f + __expf(-a));
    float om  = 1.0f - sig;
    h   = a * sig;
    sp  = sig * (1.0f + a * om);                       // silu'
    fpp = sig * om * (2.0f + a * (1.0f - 2.0f * sig)); // silu''
}

// ---------------- kernel 0: weight transposes + bf16 hi/lo split ----------------
__global__ void k_transpose(const float* __restrict__ W0, const float* __restrict__ W1,
                            const float* __restrict__ W2, const float* __restrict__ W3,
                            float* __restrict__ ws) {
    float* WT1 = ws + WT1_OFF;
    float* WT2 = ws + WT2_OFF;
    float* WT3 = ws + WT3_OFF;
    float* WT0 = ws + WT0_OFF;
    ushort* WBT = (ushort*)(ws + WBT_OFF);
    int o = blockIdx.x;      // 0..255
    int t = threadIdx.x;     // 0..255
    int which = blockIdx.y;  // 0..3
    if (which < 3) {
        const float* W = (which == 0) ? W1 : (which == 1) ? W2 : W3;
        float* WT = (which == 0) ? WT1 : (which == 1) ? WT2 : WT3;
        float v = W[t * 256 + o];
        WT[o * 256 + t] = v;
        ushort h, l;
        bsplit(v, h, l);
        WBT[(which * 2 + 0) * 65536 + o * 256 + t] = h;  // W^T hi: [n][k]
        WBT[(which * 2 + 1) * 65536 + o * 256 + t] = l;  // W^T lo
    } else if (t < 32) {
        WT0[o * 32 + t] = W0[t * 256 + o]; // WT0[i][k] = W0[k][i]
    }
}

// ---------------- kernel 1: forward + backward (16 samples/block) ----------------
__device__ __forceinline__ void fwd_layer(int L, int t, int m0,
        const float (*Hin)[SPB1], float (*Hout)[SPB1],
        const float* __restrict__ W, const float* __restrict__ b,
        float* __restrict__ f2, float* __restrict__ S)
{
    float acc[SPB1];
    #pragma unroll
    for (int s = 0; s < SPB1; ++s) acc[s] = b[t];
    const float4* H4 = (const float4*)&Hin[0][0];
    #pragma unroll 2
    for (int i = 0; i < 256; ++i) {
        float wv = W[i * 256 + t];
        #pragma unroll
        for (int q = 0; q < 4; ++q) {
            float4 h = H4[i * 4 + q];
            acc[q * 4 + 0] += h.x * wv; acc[q * 4 + 1] += h.y * wv;
            acc[q * 4 + 2] += h.z * wv; acc[q * 4 + 3] += h.w * wv;
        }
    }
    #pragma unroll
    for (int s = 0; s < SPB1; ++s) {
        float h, sp, fpp;
        silu_derivs(acc[s], h, sp, fpp);
        Hout[t][s] = h;
        S[(L * BS + m0 + s) * HID + t] = sp;
        f2[s] = fpp;
    }
}

__device__ __forceinline__ void bwd_layer(int L, int t, int m0,
        const float (*Din)[SPB1], float (*Dout)[SPB1],
        const float* __restrict__ WT,
        const float* __restrict__ f2,
        const float* __restrict__ S, float* __restrict__ C)
{
    float acc[SPB1];
    #pragma unroll
    for (int s = 0; s < SPB1; ++s) acc[s] = 0.0f;
    const float4* D4 = (const float4*)&Din[0][0];
    #pragma unroll 2
    for (int o = 0; o < 256; ++o) {
        float wv = WT[o * 256 + t];
        #pragma unroll
        for (int q = 0; q < 4; ++q) {
            float4 d = D4[o * 4 + q];
            acc[q * 4 + 0] += d.x * wv; acc[q * 4 + 1] += d.y * wv;
            acc[q * 4 + 2] += d.z * wv; acc[q * 4 + 3] += d.w * wv;
        }
    }
    #pragma unroll
    for (int s = 0; s < SPB1; ++s) {
        float dh = acc[s];
        float sl = S[(L * BS + m0 + s) * HID + t];
        C[(L * BS + m0 + s) * HID + t] = dh * f2[s];
        Dout[t][s] = dh * sl;  // delta_a
    }
}

__global__ __launch_bounds__(256) void k_stage1(
    const float* __restrict__ z,
    const float* __restrict__ W0, const float* __restrict__ b0,
    const float* __restrict__ W1, const float* __restrict__ b1,
    const float* __restrict__ W2, const float* __restrict__ b2,
    const float* __restrict__ W3, const float* __restrict__ b3,
    const float* __restrict__ W4,
    const float* __restrict__ WT0, const float* __restrict__ WT1,
    const float* __restrict__ WT2, const float* __restrict__ WT3,
    float* __restrict__ S, float* __restrict__ C, float* __restrict__ G)
{
    __shared__ __align__(16) float Zt[32][SPB1];
    __shared__ __align__(16) float Ha[256][SPB1];
    __shared__ __align__(16) float Hb[256][SPB1];
    const int t  = threadIdx.x;
    const int m0 = blockIdx.x * SPB1;
    float f2a[3][SPB1];   // silu'' for layers 0..2, thread-private (same-thread reuse)

    for (int e = t; e < 32 * SPB1; e += 256) {
        int i = e >> 4, s = e & 15;
        Zt[i][s] = z[(m0 + s) * 32 + i];
    }
    __syncthreads();

    // ---- layer 1: a1 = z @ W0 + b0 ----
    {
        float acc[SPB1];
        #pragma unroll
        for (int s = 0; s < SPB1; ++s) acc[s] = b0[t];
        const float4* Z4 = (const float4*)&Zt[0][0];
        #pragma unroll 4
        for (int i = 0; i < 32; ++i) {
            float wv = W0[i * 256 + t];
            #pragma unroll
            for (int q = 0; q < 4; ++q) {
                float4 zz = Z4[i * 4 + q];
                acc[q * 4 + 0] += zz.x * wv; acc[q * 4 + 1] += zz.y * wv;
                acc[q * 4 + 2] += zz.z * wv; acc[q * 4 + 3] += zz.w * wv;
            }
        }
        #pragma unroll
        for (int s = 0; s < SPB1; ++s) {
            float h, sp, fpp;
            silu_derivs(acc[s], h, sp, fpp);
            Ha[t][s] = h;
            S[(0 * BS + m0 + s) * HID + t] = sp;
            f2a[0][s] = fpp;
        }
    }
    __syncthreads();
    fwd_layer(1, t, m0, Ha, Hb, W1, b1, f2a[1], S);  // h2
    __syncthreads();
    fwd_layer(2, t, m0, Hb, Ha, W2, b2, f2a[2], S);  // h3
    __syncthreads();
    // ---- layer 4 + start of backward ----
    {
        float acc[SPB1];
        #pragma unroll
        for (int s = 0; s < SPB1; ++s) acc[s] = b3[t];
        const float4* H4 = (const float4*)&Ha[0][0];
        #pragma unroll 2
        for (int i = 0; i < 256; ++i) {
            float wv = W3[i * 256 + t];
            #pragma unroll
            for (int q = 0; q < 4; ++q) {
                float4 h = H4[i * 4 + q];
                acc[q * 4 + 0] += h.x * wv; acc[q * 4 + 1] += h.y * wv;
                acc[q * 4 + 2] += h.z * wv; acc[q * 4 + 3] += h.w * wv;
            }
        }
        float w4 = W4[t];
        #pragma unroll
        for (int s = 0; s < SPB1; ++s) {
            float h, sp, fpp;
            silu_derivs(acc[s], h, sp, fpp);
            Hb[t][s] = w4 * sp;                          // delta_a4
            C[(3 * BS + m0 + s) * HID + t] = w4 * fpp;   // c4
        }
    }
    __syncthreads();
    bwd_layer(2, t, m0, Hb, Ha, WT3, f2a[2], S, C);  // delta_a3 in Ha
    __syncthreads();
    bwd_layer(1, t, m0, Ha, Hb, WT2, f2a[1], S, C);  // delta_a2 in Hb
    __syncthreads();
    bwd_layer(0, t, m0, Hb, Ha, WT1, f2a[0], S, C);  // delta_a1 in Ha
    __syncthreads();
    // ---- gradient: g[k] = sum_i W0[k][i] * delta_a1[i] ----
    {
        const int k = t & 31;
        #pragma unroll
        for (int pass = 0; pass < 2; ++pass) {
            const int sh = (t >> 5) + 8 * pass;
            float acc = 0.0f;
            #pragma unroll 4
            for (int i = 0; i < 256; ++i) acc += WT0[i * 32 + k] * Ha[i][sh];
            if (k < 16) G[(m0 + sh) * 16 + k] = acc;
        }
    }
}

// ---------------- kernel 2: 32x32 MFMA tangent propagation + Hessian + solve ----
// 2 samples/block, 4 waves; wave w owns n-quarter w (tiles 2w,2w+1) for BOTH samples
// K-phase = 64 cols resident in LDS. 3-product split-bf16.
#define RS2 72   // shorts per row (144 B = 36 dwords, stride ≡ 4 mod 32 banks)

__global__ __launch_bounds__(256, 2) void k_stage2(
    const float* __restrict__ z,
    const float* __restrict__ W0,
    const ushort* __restrict__ WBT,
    const float* __restrict__ S, const float* __restrict__ C, const float* __restrict__ G,
    float* __restrict__ out)
{
    // arrays per sample: 0=ASh 1=ASl 2=ACh 3=ACl 4=TPh 5=TPl  (each 32 x RS2 shorts)
    __shared__ __align__(16) ushort SMEM[2 * 6 * 32 * RS2];   // 55296 B
    __shared__ float HCl[2][32][16];
    __shared__ float Msys2[2][16][17];
    __shared__ float vv2[2][16];

    const int t    = threadIdx.x;
    const int m0   = blockIdx.x * 2;
    const int lane = t & 63;
    const int w    = t >> 6;       // wave 0..3
    const int ln   = lane & 31;
    const int hf   = lane >> 5;

#define ARR(s, a) (&SMEM[((s) * 6 + (a)) * 32 * RS2])

    f32x16 Tacc[2][2];   // [sample][tile]  (tiles 2w, 2w+1)
    f32x16 Tnxt[2][2];
    f32x16 Dacc[2];      // [sample] Hessian accumulator

    // init T1 = W0 (same for both samples)
    #pragma unroll
    for (int tl = 0; tl < 2; ++tl) {
        #pragma unroll
        for (int r = 0; r < 16; ++r) {
            int row = (r & 3) + 8 * (r >> 2) + 4 * hf;
            float v = W0[row * HID + (2 * w + tl) * 32 + ln];
            Tacc[0][tl][r] = v;
            Tacc[1][tl][r] = v;
        }
    }
    #pragma unroll
    for (int s = 0; s < 2; ++s) {
        #pragma unroll
        for (int r = 0; r < 16; ++r) {
            Tnxt[s][0][r] = 0.0f; Tnxt[s][1][r] = 0.0f; Dacc[s][r] = 0.0f;
        }
    }

    for (int lay = 0; lay < 4; ++lay) {
        for (int p = 0; p < 4; ++p) {
            // ---------- epilogue: wave p writes split arrays for cols 64p..64p+63 ----
            if (w == p) {
                #pragma unroll
                for (int s = 0; s < 2; ++s) {
                    #pragma unroll
                    for (int tl = 0; tl < 2; ++tl) {
                        const int cg = (2 * p + tl) * 32 + ln;
                        const int cl = tl * 32 + ln;
                        const float sv = (lay < 3) ? S[(lay * BS + m0 + s) * HID + cg] : 0.0f;
                        const float cv = C[(lay * BS + m0 + s) * HID + cg];
                        #pragma unroll
                        for (int r = 0; r < 16; ++r) {
                            const int row = (r & 3) + 8 * (r >> 2) + 4 * hf;
                            const float tv = Tacc[s][tl][r];
                            ushort h, l;
                            if (lay < 3) {
                                bsplit(sv * tv, h, l);
                                ARR(s, 0)[row * RS2 + cl] = h;
                                ARR(s, 1)[row * RS2 + cl] = l;
                            }
                            bsplit(cv * tv, h, l);
                            ARR(s, 2)[row * RS2 + cl] = h;
                            ARR(s, 3)[row * RS2 + cl] = l;
                            if (r >= 8) {  // rows 16..31
                                bsplit(tv, h, l);
                                ARR(s, 4)[(row - 16) * RS2 + cl] = h;
                                ARR(s, 5)[(row - 16) * RS2 + cl] = l;
                            }
                        }
                    }
                }
            }
            __syncthreads();

            // ---------- contraction: wave w handles k-chunk ks=w of this phase ------
            {
                const int ko = w * 16 + hf * 8;
                #pragma unroll
                for (int s = 0; s < 2; ++s) {
                    bf16x8 Bh = *(const bf16x8*)&ARR(s, 4)[ln * RS2 + ko];
                    bf16x8 Bl = *(const bf16x8*)&ARR(s, 5)[ln * RS2 + ko];
                    bf16x8 Ah = *(const bf16x8*)&ARR(s, 2)[ln * RS2 + ko];
                    bf16x8 Al = *(const bf16x8*)&ARR(s, 3)[ln * RS2 + ko];
                    Dacc[s] = MFMA32(Ah, Bh, MFMA32(Al, Bh, MFMA32(Ah, Bl, Dacc[s])));
                }
            }

            // ---------- GEMM: Tnxt += (s.T) @ W_{lay+1}, this phase's K ------------
            if (lay < 3) {
                const ushort* WH = WBT + (lay * 2 + 0) * 65536;
                const ushort* WL = WBT + (lay * 2 + 1) * 65536;
                #pragma unroll
                for (int ks = 0; ks < 4; ++ks) {
                    const int ko = ks * 16 + hf * 8;
                    bf16x8 Ah[2], Al[2];
                    #pragma unroll
                    for (int s = 0; s < 2; ++s) {
                        Ah[s] = *(const bf16x8*)&ARR(s, 0)[ln * RS2 + ko];
                        Al[s] = *(const bf16x8*)&ARR(s, 1)[ln * RS2 + ko];
                    }
                    const int kg = p * 64 + ko;
                    #pragma unroll
                    for (int nt = 0; nt < 2; ++nt) {
                        const int nr = w * 64 + nt * 32 + ln;
                        bf16x8 Bh = *(const bf16x8*)&WH[nr * 256 + kg];
                        bf16x8 Bl = *(const bf16x8*)&WL[nr * 256 + kg];
                        #pragma unroll
                        for (int s = 0; s < 2; ++s) {
                            Tnxt[s][nt] = MFMA32(Ah[s], Bh,
                                          MFMA32(Al[s], Bh,
                                          MFMA32(Ah[s], Bl, Tnxt[s][nt])));
                        }
                    }
                }
            }
            __syncthreads();
        } // p

        if (lay < 3) {
            #pragma unroll
            for (int s = 0; s < 2; ++s)
                #pragma unroll
                for (int tl = 0; tl < 2; ++tl) {
                    Tacc[s][tl] = Tnxt[s][tl];
                    #pragma unroll
                    for (int r = 0; r < 16; ++r) Tnxt[s][tl][r] = 0.0f;
                }
        }
    } // lay

    // ---------- reduce Hessian partials (overlay Dred on SMEM) ----------
    float* Dred = (float*)SMEM;   // [wave][sample][reg][lane] = 32 KB
    #pragma unroll
    for (int s = 0; s < 2; ++s)
        #pragma unroll
        for (int r = 0; r < 16; ++r)
            Dred[((w * 2 + s) * 16 + r) * 64 + lane] = Dacc[s][r];
    __syncthreads();

    // ---------- per-wave solve (wave 0 -> sample 0, wave 1 -> sample 1) ----------
    if (w < 2) {
        const int s = w;
        #pragma unroll
        for (int r = 0; r < 16; ++r) {
            float v = 0.0f;
            #pragma unroll
            for (int wv = 0; wv < 4; ++wv)
                v += Dred[((wv * 2 + s) * 16 + r) * 64 + lane];
            const int row = (r & 3) + 8 * (r >> 2) + 4 * hf;
            if (ln < 16) HCl[s][row][ln] = v;   // HC[k][j] = H[k][16+j]
        }

        float* M = &Msys2[s][0][0];   // [16][17]
        float vr = 0.0f;
        if (lane < 16) {
            vr = z[(m0 + s) * 32 + 16 + lane];
            vv2[s][lane] = vr;
        }
        if (lane < 16) {
            #pragma unroll
            for (int j = 0; j < 16; ++j)
                M[lane * 17 + j] = HCl[s][16 + lane][j] + (lane == j ? 0.2f : 0.0f);
            float r = G[(m0 + s) * 16 + lane];
            #pragma unroll
            for (int j = 0; j < 16; ++j)
                r -= HCl[s][j][lane] * vv2[s][j];
            M[lane * 17 + 16] = r;
        }
        // Gauss-Jordan with partial pivoting (wave-synchronous)
        for (int k2 = 0; k2 < 16; ++k2) {
            float val = (lane < 16 && lane >= k2) ? fabsf(M[lane * 17 + k2]) : -1.0f;
            int idx = lane;
            #pragma unroll
            for (int off = 8; off > 0; off >>= 1) {
                float ov = __shfl_xor(val, off, 64);
                int oi = __shfl_xor(idx, off, 64);
                if (ov > val) { val = ov; idx = oi; }
            }
            const int p2 = __shfl(idx, 0, 64);
            if (p2 != k2 && lane < 17) {
                float tmp = M[k2 * 17 + lane];
                M[k2 * 17 + lane] = M[p2 * 17 + lane];
                M[p2 * 17 + lane] = tmp;
            }
            if (lane < 16) {
                const float f = (lane == k2) ? 0.0f : M[lane * 17 + k2] / M[k2 * 17 + k2];
                #pragma unroll
                for (int j = 0; j < 17; ++j)
                    M[lane * 17 + j] -= f * M[k2 * 17 + j];
            }
        }
        if (lane < 16) {
            out[(m0 + s) * 32 + lane]      = vr;
            out[(m0 + s) * 32 + 16 + lane] = M[lane * 17 + 16] / M[lane * 17 + lane];
        }
    }
#undef ARR
}

extern "C" void kernel_launch(void* const* d_in, const int* in_sizes, int n_in,
                              void* d_out, int out_size, void* d_ws, size_t ws_size,
                              hipStream_t stream) {
    const float* z  = (const float*)d_in[1];
    const float* W0 = (const float*)d_in[2];
    const float* b0 = (const float*)d_in[3];
    const float* W1 = (const float*)d_in[4];
    const float* b1 = (const float*)d_in[5];
    const float* W2 = (const float*)d_in[6];
    const float* b2 = (const float*)d_in[7];
    const float* W3 = (const float*)d_in[8];
    const float* b3 = (const float*)d_in[9];
    const float* W4 = (const float*)d_in[10];
    float* out = (float*)d_out;
    float* ws  = (float*)d_ws;

    float* WT1 = ws + WT1_OFF;
    float* WT2 = ws + WT2_OFF;
    float* WT3 = ws + WT3_OFF;
    float* WT0 = ws + WT0_OFF;
    float* S   = ws + S_OFF;
    float* C   = ws + C_OFF;
    float* G   = ws + G_OFF;
    const ushort* WBT = (const ushort*)(ws + WBT_OFF);

    k_transpose<<<dim3(256, 4), 256, 0, stream>>>(W0, W1, W2, W3, ws);
    k_stage1<<<BS / SPB1, 256, 0, stream>>>(z, W0, b0, W1, b1, W2, b2, W3, b3, W4,
                                            WT0, WT1, WT2, WT3, S, C, G);
    k_stage2<<<BS / 2, 256, 0, stream>>>(z, W0, WBT, S, C, G, out);
}

// Round 5
// 1473.580 us; speedup vs baseline: 2.4363x; 2.4363x over previous
//
#include <hip/hip_runtime.h>
#include <math.h>

#define BS 8192
#define HID 256
#define SPB1 8

// ---- workspace layout (float element offsets) ----
#define WT1_OFF 0
#define WT2_OFF 65536
#define WT3_OFF 131072
#define WT0_OFF 196608
#define S_OFF   204800
#define C_OFF   (S_OFF + 4 * BS * HID)
#define G_OFF   (C_OFF + 4 * BS * HID)
#define WBT_OFF (G_OFF + BS * 16)
// WBT region: 3 layers x 2 (hi,lo) x 256 x 256 ushort = 786432 B after WBT_OFF floats

typedef __attribute__((ext_vector_type(8))) short bf16x8;
typedef __attribute__((ext_vector_type(16))) float f32x16;
#define MFMA32(A, B, C) __builtin_amdgcn_mfma_f32_32x32x16_bf16(A, B, C, 0, 0, 0)

__device__ __forceinline__ ushort bf16_rne(float x) {
    unsigned u = __float_as_uint(x);
    unsigned r = u + 0x7FFFu + ((u >> 16) & 1u);
    return (ushort)(r >> 16);
}
__device__ __forceinline__ void bsplit(float x, ushort& hi, ushort& lo) {
    hi = bf16_rne(x);
    float hf = __uint_as_float(((unsigned)hi) << 16);
    lo = bf16_rne(x - hf);
}
// split 8 floats into hi/lo bf16 uint4 packs
__device__ __forceinline__ void split8(const float* v, uint4& H, uint4& L) {
    ushort h[8], l[8];
    #pragma unroll
    for (int e = 0; e < 8; ++e) bsplit(v[e], h[e], l[e]);
    H.x = (uint)h[0] | ((uint)h[1] << 16); H.y = (uint)h[2] | ((uint)h[3] << 16);
    H.z = (uint)h[4] | ((uint)h[5] << 16); H.w = (uint)h[6] | ((uint)h[7] << 16);
    L.x = (uint)l[0] | ((uint)l[1] << 16); L.y = (uint)l[2] | ((uint)l[3] << 16);
    L.z = (uint)l[4] | ((uint)l[5] << 16); L.w = (uint)l[6] | ((uint)l[7] << 16);
}

__device__ __forceinline__ void silu_derivs(float a, float& h, float& sp, float& fpp) {
    float sig = 1.0f / (1.0f + __expf(-a));
    float om  = 1.0f - sig;
    h   = a * sig;
    sp  = sig * (1.0f + a * om);                       // silu'
    fpp = sig * om * (2.0f + a * (1.0f - 2.0f * sig)); // silu''
}

// ---------------- kernel 0: weight transposes + bf16 hi/lo split ----------------
__global__ void k_transpose(const float* __restrict__ W0, const float* __restrict__ W1,
                            const float* __restrict__ W2, const float* __restrict__ W3,
                            float* __restrict__ ws) {
    float* WT1 = ws + WT1_OFF;
    float* WT2 = ws + WT2_OFF;
    float* WT3 = ws + WT3_OFF;
    float* WT0 = ws + WT0_OFF;
    ushort* WBT = (ushort*)(ws + WBT_OFF);
    int o = blockIdx.x;      // 0..255
    int t = threadIdx.x;     // 0..255
    int which = blockIdx.y;  // 0..3
    if (which < 3) {
        const float* W = (which == 0) ? W1 : (which == 1) ? W2 : W3;
        float* WT = (which == 0) ? WT1 : (which == 1) ? WT2 : WT3;
        float v = W[t * 256 + o];
        WT[o * 256 + t] = v;
        ushort h, l;
        bsplit(v, h, l);
        WBT[(which * 2 + 0) * 65536 + o * 256 + t] = h;  // W^T hi: [n][k]
        WBT[(which * 2 + 1) * 65536 + o * 256 + t] = l;  // W^T lo
    } else if (t < 32) {
        WT0[o * 32 + t] = W0[t * 256 + o]; // WT0[i][k] = W0[k][i]
    }
}

// ---------------- kernel 1: forward + backward (8 samples/block, R2-proven) ----
__device__ __forceinline__ void fwd_layer(int L, int t, int m0,
        const float (*Hin)[SPB1], float (*Hout)[SPB1],
        const float* __restrict__ W, const float* __restrict__ b,
        float (*F2l)[SPB1], float* __restrict__ S)
{
    float acc[SPB1];
    #pragma unroll
    for (int s = 0; s < SPB1; ++s) acc[s] = b[t];
    const float4* H4 = (const float4*)&Hin[0][0];
    #pragma unroll 4
    for (int i = 0; i < 256; ++i) {
        float w = W[i * 256 + t];
        float4 h0 = H4[i * 2 + 0];
        float4 h1 = H4[i * 2 + 1];
        acc[0] += h0.x * w; acc[1] += h0.y * w; acc[2] += h0.z * w; acc[3] += h0.w * w;
        acc[4] += h1.x * w; acc[5] += h1.y * w; acc[6] += h1.z * w; acc[7] += h1.w * w;
    }
    #pragma unroll
    for (int s = 0; s < SPB1; ++s) {
        float h, sp, fpp;
        silu_derivs(acc[s], h, sp, fpp);
        Hout[t][s] = h;
        S[(L * BS + m0 + s) * HID + t] = sp;
        F2l[t][s] = fpp;
    }
}

__device__ __forceinline__ void bwd_layer(int L, int t, int m0,
        const float (*Din)[SPB1], float (*Dout)[SPB1],
        const float* __restrict__ WT,
        const float (*F2l)[SPB1],
        const float* __restrict__ S, float* __restrict__ C)
{
    float acc[SPB1];
    #pragma unroll
    for (int s = 0; s < SPB1; ++s) acc[s] = 0.0f;
    const float4* D4 = (const float4*)&Din[0][0];
    #pragma unroll 4
    for (int o = 0; o < 256; ++o) {
        float w = WT[o * 256 + t];
        float4 d0 = D4[o * 2 + 0];
        float4 d1 = D4[o * 2 + 1];
        acc[0] += d0.x * w; acc[1] += d0.y * w; acc[2] += d0.z * w; acc[3] += d0.w * w;
        acc[4] += d1.x * w; acc[5] += d1.y * w; acc[6] += d1.z * w; acc[7] += d1.w * w;
    }
    #pragma unroll
    for (int s = 0; s < SPB1; ++s) {
        float dh = acc[s];
        float sl = S[(L * BS + m0 + s) * HID + t];
        C[(L * BS + m0 + s) * HID + t] = dh * F2l[t][s];
        Dout[t][s] = dh * sl;  // delta_a
    }
}

__global__ __launch_bounds__(256) void k_stage1(
    const float* __restrict__ z,
    const float* __restrict__ W0, const float* __restrict__ b0,
    const float* __restrict__ W1, const float* __restrict__ b1,
    const float* __restrict__ W2, const float* __restrict__ b2,
    const float* __restrict__ W3, const float* __restrict__ b3,
    const float* __restrict__ W4,
    const float* __restrict__ WT0, const float* __restrict__ WT1,
    const float* __restrict__ WT2, const float* __restrict__ WT3,
    float* __restrict__ S, float* __restrict__ C, float* __restrict__ G)
{
    __shared__ __align__(16) float Zt[SPB1][32];
    __shared__ __align__(16) float Ha[256][SPB1];
    __shared__ __align__(16) float Hb[256][SPB1];
    __shared__ __align__(16) float F2s[4][256][SPB1];
    const int t  = threadIdx.x;
    const int m0 = blockIdx.x * SPB1;

    Zt[t >> 5][t & 31] = z[(m0 + (t >> 5)) * 32 + (t & 31)];
    __syncthreads();

    // ---- layer 1: a1 = z @ W0 + b0 ----
    {
        float acc[SPB1];
        #pragma unroll
        for (int s = 0; s < SPB1; ++s) acc[s] = b0[t];
        #pragma unroll 8
        for (int i = 0; i < 32; ++i) {
            float w = W0[i * 256 + t];
            #pragma unroll
            for (int s = 0; s < SPB1; ++s) acc[s] += Zt[s][i] * w;
        }
        #pragma unroll
        for (int s = 0; s < SPB1; ++s) {
            float h, sp, fpp;
            silu_derivs(acc[s], h, sp, fpp);
            Ha[t][s] = h;
            S[(0 * BS + m0 + s) * HID + t] = sp;
            F2s[0][t][s] = fpp;
        }
    }
    __syncthreads();
    fwd_layer(1, t, m0, Ha, Hb, W1, b1, F2s[1], S);  // h2
    __syncthreads();
    fwd_layer(2, t, m0, Hb, Ha, W2, b2, F2s[2], S);  // h3
    __syncthreads();
    // ---- layer 4 + start of backward ----
    {
        float acc[SPB1];
        #pragma unroll
        for (int s = 0; s < SPB1; ++s) acc[s] = b3[t];
        const float4* H4 = (const float4*)&Ha[0][0];
        #pragma unroll 4
        for (int i = 0; i < 256; ++i) {
            float w = W3[i * 256 + t];
            float4 h0 = H4[i * 2 + 0];
            float4 h1 = H4[i * 2 + 1];
            acc[0] += h0.x * w; acc[1] += h0.y * w; acc[2] += h0.z * w; acc[3] += h0.w * w;
            acc[4] += h1.x * w; acc[5] += h1.y * w; acc[6] += h1.z * w; acc[7] += h1.w * w;
        }
        float w4 = W4[t];
        #pragma unroll
        for (int s = 0; s < SPB1; ++s) {
            float h, sp, fpp;
            silu_derivs(acc[s], h, sp, fpp);
            Hb[t][s] = w4 * sp;                          // delta_a4
            C[(3 * BS + m0 + s) * HID + t] = w4 * fpp;   // c4
        }
    }
    __syncthreads();
    bwd_layer(2, t, m0, Hb, Ha, WT3, F2s[2], S, C);  // delta_a3 in Ha
    __syncthreads();
    bwd_layer(1, t, m0, Ha, Hb, WT2, F2s[1], S, C);  // delta_a2 in Hb
    __syncthreads();
    bwd_layer(0, t, m0, Hb, Ha, WT1, F2s[0], S, C);  // delta_a1 in Ha
    __syncthreads();
    // ---- gradient: g[k] = sum_i W0[k][i] * delta_a1[i] ----
    {
        const int k = t & 31, sh = t >> 5;
        float acc = 0.0f;
        #pragma unroll 4
        for (int i = 0; i < 256; ++i) acc += WT0[i * 32 + k] * Ha[i][sh];
        if (k < 16) G[(m0 + sh) * 16 + k] = acc;
    }
}

// ---------------- kernel 2: 32x32 MFMA tangent propagation + Hessian + solve ----
// 1 sample/block, 4 waves; wave w owns output cols 64w..64w+63.
// T (fp32) lives in LDS; epilogue (scale+split) parallel across all waves.
#define RS2 72     // shorts per row (144 B) — conflict-free (R3-measured)
#define TFPAD 260  // floats per Tf row

__global__ __launch_bounds__(256, 2) void k_stage2(
    const float* __restrict__ z,
    const float* __restrict__ W0,
    const ushort* __restrict__ WBT,
    const float* __restrict__ S, const float* __restrict__ C, const float* __restrict__ G,
    float* __restrict__ out)
{
    // slots: 0=ASh 1=ASl 2=ACh 3=ACl 4=TPh 5=TPl  (each 32 x RS2 shorts)
    __shared__ __align__(16) ushort SMEM[6 * 32 * RS2];   // 27648 B
    __shared__ __align__(16) float Tf[32 * TFPAD];        // 33280 B
    __shared__ float HCl[32][16];
    __shared__ float Msys[16][17];
    __shared__ float vvs[16];

    const int t    = threadIdx.x;
    const int m    = blockIdx.x;
    const int lane = t & 63;
    const int w    = t >> 6;       // wave 0..3
    const int ln   = lane & 31;
    const int hf   = lane >> 5;
    const int er   = t >> 3;          // epilogue row 0..31
    const int ej   = (t & 7) * 8;     // epilogue col offset 0,8,..56

#define SLOT(a) (&SMEM[(a) * 32 * RS2])

    f32x16 Tnxt[2];
    f32x16 Dacc;
    #pragma unroll
    for (int r = 0; r < 16; ++r) { Tnxt[0][r] = 0.0f; Tnxt[1][r] = 0.0f; Dacc[r] = 0.0f; }

    // init Tf = T1 = W0  (T1[k][i] = W0[k][i]) — ALL FOUR column quarters (R4 bug fix)
    #pragma unroll
    for (int q = 0; q < 4; ++q) {
        const int c = q * 64 + ej;
        float4 a = *(const float4*)&W0[er * HID + c];
        float4 b = *(const float4*)&W0[er * HID + c + 4];
        *(float4*)&Tf[er * TFPAD + c]     = a;
        *(float4*)&Tf[er * TFPAD + c + 4] = b;
    }
    __syncthreads();

    for (int lay = 0; lay < 4; ++lay) {
        for (int p = 0; p < 4; ++p) {
            // ---------- epilogue: all 256 threads split-scale phase-p cols ----------
            {
                const int cg = p * 64 + ej;
                float tv[8], tmp[8];
                *(float4*)&tv[0] = *(const float4*)&Tf[er * TFPAD + cg];
                *(float4*)&tv[4] = *(const float4*)&Tf[er * TFPAD + cg + 4];
                float4 c0 = *(const float4*)&C[(lay * BS + m) * HID + cg];
                float4 c1 = *(const float4*)&C[(lay * BS + m) * HID + cg + 4];
                uint4 H, L;
                tmp[0] = c0.x * tv[0]; tmp[1] = c0.y * tv[1];
                tmp[2] = c0.z * tv[2]; tmp[3] = c0.w * tv[3];
                tmp[4] = c1.x * tv[4]; tmp[5] = c1.y * tv[5];
                tmp[6] = c1.z * tv[6]; tmp[7] = c1.w * tv[7];
                split8(tmp, H, L);
                *(uint4*)(SLOT(2) + er * RS2 + ej) = H;
                *(uint4*)(SLOT(3) + er * RS2 + ej) = L;
                if (lay < 3) {
                    float4 s0 = *(const float4*)&S[(lay * BS + m) * HID + cg];
                    float4 s1 = *(const float4*)&S[(lay * BS + m) * HID + cg + 4];
                    tmp[0] = s0.x * tv[0]; tmp[1] = s0.y * tv[1];
                    tmp[2] = s0.z * tv[2]; tmp[3] = s0.w * tv[3];
                    tmp[4] = s1.x * tv[4]; tmp[5] = s1.y * tv[5];
                    tmp[6] = s1.z * tv[6]; tmp[7] = s1.w * tv[7];
                    split8(tmp, H, L);
                    *(uint4*)(SLOT(0) + er * RS2 + ej) = H;
                    *(uint4*)(SLOT(1) + er * RS2 + ej) = L;
                }
                if (er >= 16) {   // waves 2,3 — wave-uniform branch
                    split8(tv, H, L);
                    *(uint4*)(SLOT(4) + (er - 16) * RS2 + ej) = H;
                    *(uint4*)(SLOT(5) + (er - 16) * RS2 + ej) = L;
                }
            }
            __syncthreads();

            // ---------- contraction: HC += (c.T) x Tp^T, wave w takes K-chunk w ----
            {
                const int ko = w * 16 + hf * 8;
                bf16x8 Bh = *(const bf16x8*)(SLOT(4) + ln * RS2 + ko);
                bf16x8 Bl = *(const bf16x8*)(SLOT(5) + ln * RS2 + ko);
                bf16x8 Ah = *(const bf16x8*)(SLOT(2) + ln * RS2 + ko);
                bf16x8 Al = *(const bf16x8*)(SLOT(3) + ln * RS2 + ko);
                Dacc = MFMA32(Ah, Bh, MFMA32(Al, Bh, MFMA32(Ah, Bl, Dacc)));
            }

            // ---------- GEMM: Tnxt += (s.T) @ W_{lay+1} over this phase's K --------
            if (lay < 3) {
                const ushort* WH = WBT + (lay * 2 + 0) * 65536;
                const ushort* WL = WBT + (lay * 2 + 1) * 65536;
                #pragma unroll
                for (int ks = 0; ks < 4; ++ks) {
                    const int ko = ks * 16 + hf * 8;
                    bf16x8 Ah = *(const bf16x8*)(SLOT(0) + ln * RS2 + ko);
                    bf16x8 Al = *(const bf16x8*)(SLOT(1) + ln * RS2 + ko);
                    const int kg = p * 64 + ko;
                    #pragma unroll
                    for (int nt = 0; nt < 2; ++nt) {
                        const int nr = w * 64 + nt * 32 + ln;
                        bf16x8 Bh = *(const bf16x8*)&WH[nr * 256 + kg];
                        bf16x8 Bl = *(const bf16x8*)&WL[nr * 256 + kg];
                        Tnxt[nt] = MFMA32(Ah, Bh,
                                   MFMA32(Al, Bh,
                                   MFMA32(Ah, Bl, Tnxt[nt])));
                    }
                }
            }
            __syncthreads();
        } // p

        // ---------- layer end: Tf <- Tnxt, reset ----------
        if (lay < 3) {
            #pragma unroll
            for (int nt = 0; nt < 2; ++nt) {
                const int col = w * 64 + nt * 32 + ln;
                #pragma unroll
                for (int r = 0; r < 16; ++r) {
                    const int row = (r & 3) + 8 * (r >> 2) + 4 * hf;
                    Tf[row * TFPAD + col] = Tnxt[nt][r];
                    Tnxt[nt][r] = 0.0f;
                }
            }
            __syncthreads();
        }
    } // lay

    // ---------- reduce Hessian partials across waves (overlay on SMEM) ----------
    float* Dred = (float*)SMEM;   // 4*16*64*4 = 16 KB <= 27.6 KB
    #pragma unroll
    for (int r = 0; r < 16; ++r)
        Dred[(w * 16 + r) * 64 + lane] = Dacc[r];
    __syncthreads();

    // ---------- wave-0 solve ----------
    if (w == 0) {
        #pragma unroll
        for (int r = 0; r < 16; ++r) {
            float v = Dred[r * 64 + lane] + Dred[(16 + r) * 64 + lane]
                    + Dred[(32 + r) * 64 + lane] + Dred[(48 + r) * 64 + lane];
            const int row = (r & 3) + 8 * (r >> 2) + 4 * hf;
            if (ln < 16) HCl[row][ln] = v;   // HC[k][j] = H[k][16+j]
        }

        float* M = &Msys[0][0];   // [16][17]
        float vr = 0.0f;
        if (lane < 16) {
            vr = z[m * 32 + 16 + lane];
            vvs[lane] = vr;
        }
        if (lane < 16) {
            #pragma unroll
            for (int j = 0; j < 16; ++j)
                M[lane * 17 + j] = HCl[16 + lane][j] + (lane == j ? 0.2f : 0.0f);
            float r = G[m * 16 + lane];
            #pragma unroll
            for (int j = 0; j < 16; ++j)
                r -= HCl[j][lane] * vvs[j];
            M[lane * 17 + 16] = r;
        }
        // Gauss-Jordan with partial pivoting (wave-synchronous)
        for (int k2 = 0; k2 < 16; ++k2) {
            float val = (lane < 16 && lane >= k2) ? fabsf(M[lane * 17 + k2]) : -1.0f;
            int idx = lane;
            #pragma unroll
            for (int off = 8; off > 0; off >>= 1) {
                float ov = __shfl_xor(val, off, 64);
                int oi = __shfl_xor(idx, off, 64);
                if (ov > val) { val = ov; idx = oi; }
            }
            const int p2 = __shfl(idx, 0, 64);
            if (p2 != k2 && lane < 17) {
                float tmp = M[k2 * 17 + lane];
                M[k2 * 17 + lane] = M[p2 * 17 + lane];
                M[p2 * 17 + lane] = tmp;
            }
            if (lane < 16) {
                const float f = (lane == k2) ? 0.0f : M[lane * 17 + k2] / M[k2 * 17 + k2];
                #pragma unroll
                for (int j = 0; j < 17; ++j)
                    M[lane * 17 + j] -= f * M[k2 * 17 + j];
            }
        }
        if (lane < 16) {
            out[m * 32 + lane]      = vr;
            out[m * 32 + 16 + lane] = M[lane * 17 + 16] / M[lane * 17 + lane];
        }
    }
#undef SLOT
}

extern "C" void kernel_launch(void* const* d_in, const int* in_sizes, int n_in,
                              void* d_out, int out_size, void* d_ws, size_t ws_size,
                              hipStream_t stream) {
    const float* z  = (const float*)d_in[1];
    const float* W0 = (const float*)d_in[2];
    const float* b0 = (const float*)d_in[3];
    const float* W1 = (const float*)d_in[4];
    const float* b1 = (const float*)d_in[5];
    const float* W2 = (const float*)d_in[6];
    const float* b2 = (const float*)d_in[7];
    const float* W3 = (const float*)d_in[8];
    const float* b3 = (const float*)d_in[9];
    const float* W4 = (const float*)d_in[10];
    float* out = (float*)d_out;
    float* ws  = (float*)d_ws;

    float* WT1 = ws + WT1_OFF;
    float* WT2 = ws + WT2_OFF;
    float* WT3 = ws + WT3_OFF;
    float* WT0 = ws + WT0_OFF;
    float* S   = ws + S_OFF;
    float* C   = ws + C_OFF;
    float* G   = ws + G_OFF;
    const ushort* WBT = (const ushort*)(ws + WBT_OFF);

    k_transpose<<<dim3(256, 4), 256, 0, stream>>>(W0, W1, W2, W3, ws);
    k_stage1<<<BS / SPB1, 256, 0, stream>>>(z, W0, b0, W1, b1, W2, b2, W3, b3, W4,
                                            WT0, WT1, WT2, WT3, S, C, G);
    k_stage2<<<BS, 256, 0, stream>>>(z, W0, WBT, S, C, G, out);
}

// Round 6
// 1270.010 us; speedup vs baseline: 2.8268x; 1.1603x over previous
//
#include <hip/hip_runtime.h>
#include <hip/hip_bf16.h>
#include <math.h>

#define BS 8192
#define HID 256
#define SPB1 8

// ---- workspace layout (float element offsets) ----
#define WT1_OFF 0
#define WT2_OFF 65536
#define WT3_OFF 131072
#define WT0_OFF 196608
#define S_OFF   204800
#define C_OFF   (S_OFF + 4 * BS * HID)
#define G_OFF   (C_OFF + 4 * BS * HID)
#define WBT_OFF (G_OFF + BS * 16)
// WBT region: 3 layers x 2 (hi,lo) x 256 x 256 ushort = 786432 B after WBT_OFF floats

typedef __attribute__((ext_vector_type(8))) short bf16x8;
typedef __attribute__((ext_vector_type(16))) float f32x16;
#define MFMA32(A, B, C) __builtin_amdgcn_mfma_f32_32x32x16_bf16(A, B, C, 0, 0, 0)

__device__ __forceinline__ ushort bf16_rne(float x) {
    unsigned u = __float_as_uint(x);
    unsigned r = u + 0x7FFFu + ((u >> 16) & 1u);
    return (ushort)(r >> 16);
}
__device__ __forceinline__ void bsplit(float x, ushort& hi, ushort& lo) {
    hi = bf16_rne(x);
    float hf = __uint_as_float(((unsigned)hi) << 16);
    lo = bf16_rne(x - hf);
}

// packed split via v_cvt_pk_bf16_f32 (gfx950): 2 elements -> hi uint, lo uint
__device__ __forceinline__ uint pk2(float a, float b) {
    __hip_bfloat162 h = __float22bfloat162_rn(float2{a, b});
    uint u; __builtin_memcpy(&u, &h, 4); return u;
}
__device__ __forceinline__ void split2(float a, float b, uint& hp, uint& lp) {
    hp = pk2(a, b);
    float ha = __uint_as_float(hp << 16);
    float hb = __uint_as_float(hp & 0xFFFF0000u);
    lp = pk2(a - ha, b - hb);
}
__device__ __forceinline__ void split8v(const float* v, uint4& H, uint4& L) {
    split2(v[0], v[1], H.x, L.x);
    split2(v[2], v[3], H.y, L.y);
    split2(v[4], v[5], H.z, L.z);
    split2(v[6], v[7], H.w, L.w);
}

__device__ __forceinline__ void silu_derivs(float a, float& h, float& sp, float& fpp) {
    float sig = 1.0f / (1.0f + __expf(-a));
    float om  = 1.0f - sig;
    h   = a * sig;
    sp  = sig * (1.0f + a * om);                       // silu'
    fpp = sig * om * (2.0f + a * (1.0f - 2.0f * sig)); // silu''
}

// ---------------- kernel 0: weight transposes + bf16 hi/lo split ----------------
__global__ void k_transpose(const float* __restrict__ W0, const float* __restrict__ W1,
                            const float* __restrict__ W2, const float* __restrict__ W3,
                            float* __restrict__ ws) {
    float* WT1 = ws + WT1_OFF;
    float* WT2 = ws + WT2_OFF;
    float* WT3 = ws + WT3_OFF;
    float* WT0 = ws + WT0_OFF;
    ushort* WBT = (ushort*)(ws + WBT_OFF);
    int o = blockIdx.x;      // 0..255
    int t = threadIdx.x;     // 0..255
    int which = blockIdx.y;  // 0..3
    if (which < 3) {
        const float* W = (which == 0) ? W1 : (which == 1) ? W2 : W3;
        float* WT = (which == 0) ? WT1 : (which == 1) ? WT2 : WT3;
        float v = W[t * 256 + o];
        WT[o * 256 + t] = v;
        ushort h, l;
        bsplit(v, h, l);
        WBT[(which * 2 + 0) * 65536 + o * 256 + t] = h;  // W^T hi: [n][k]
        WBT[(which * 2 + 1) * 65536 + o * 256 + t] = l;  // W^T lo
    } else if (t < 32) {
        WT0[o * 32 + t] = W0[t * 256 + o]; // WT0[i][k] = W0[k][i]
    }
}

// ---------------- kernel 1: forward + backward (8 samples/block) ----------------
__device__ __forceinline__ void fwd_layer(int L, int t, int m0,
        const float (*Hin)[SPB1], float (*Hout)[SPB1],
        const float* __restrict__ W, const float* __restrict__ b,
        float* __restrict__ f2, float* __restrict__ S)
{
    float acc[SPB1];
    #pragma unroll
    for (int s = 0; s < SPB1; ++s) acc[s] = b[t];
    const float4* H4 = (const float4*)&Hin[0][0];
    #pragma unroll 4
    for (int i = 0; i < 256; ++i) {
        float w = W[i * 256 + t];
        float4 h0 = H4[i * 2 + 0];
        float4 h1 = H4[i * 2 + 1];
        acc[0] += h0.x * w; acc[1] += h0.y * w; acc[2] += h0.z * w; acc[3] += h0.w * w;
        acc[4] += h1.x * w; acc[5] += h1.y * w; acc[6] += h1.z * w; acc[7] += h1.w * w;
    }
    #pragma unroll
    for (int s = 0; s < SPB1; ++s) {
        float h, sp, fpp;
        silu_derivs(acc[s], h, sp, fpp);
        Hout[t][s] = h;
        S[(L * BS + m0 + s) * HID + t] = sp;
        f2[s] = fpp;
    }
}

__device__ __forceinline__ void bwd_layer(int L, int t, int m0,
        const float (*Din)[SPB1], float (*Dout)[SPB1],
        const float* __restrict__ WT,
        const float* __restrict__ f2,
        const float* __restrict__ S, float* __restrict__ C)
{
    float acc[SPB1];
    #pragma unroll
    for (int s = 0; s < SPB1; ++s) acc[s] = 0.0f;
    const float4* D4 = (const float4*)&Din[0][0];
    #pragma unroll 4
    for (int o = 0; o < 256; ++o) {
        float w = WT[o * 256 + t];
        float4 d0 = D4[o * 2 + 0];
        float4 d1 = D4[o * 2 + 1];
        acc[0] += d0.x * w; acc[1] += d0.y * w; acc[2] += d0.z * w; acc[3] += d0.w * w;
        acc[4] += d1.x * w; acc[5] += d1.y * w; acc[6] += d1.z * w; acc[7] += d1.w * w;
    }
    #pragma unroll
    for (int s = 0; s < SPB1; ++s) {
        float dh = acc[s];
        float sl = S[(L * BS + m0 + s) * HID + t];
        C[(L * BS + m0 + s) * HID + t] = dh * f2[s];
        Dout[t][s] = dh * sl;  // delta_a
    }
}

__global__ __launch_bounds__(256) void k_stage1(
    const float* __restrict__ z,
    const float* __restrict__ W0, const float* __restrict__ b0,
    const float* __restrict__ W1, const float* __restrict__ b1,
    const float* __restrict__ W2, const float* __restrict__ b2,
    const float* __restrict__ W3, const float* __restrict__ b3,
    const float* __restrict__ W4,
    const float* __restrict__ WT0, const float* __restrict__ WT1,
    const float* __restrict__ WT2, const float* __restrict__ WT3,
    float* __restrict__ S, float* __restrict__ C, float* __restrict__ G)
{
    __shared__ __align__(16) float Zt[SPB1][32];
    __shared__ __align__(16) float Ha[256][SPB1];
    __shared__ __align__(16) float Hb[256][SPB1];
    const int t  = threadIdx.x;
    const int m0 = blockIdx.x * SPB1;
    float f2a[3][SPB1];   // silu'' layers 0..2: same-thread produce/consume

    Zt[t >> 5][t & 31] = z[(m0 + (t >> 5)) * 32 + (t & 31)];
    __syncthreads();

    // ---- layer 1: a1 = z @ W0 + b0 ----
    {
        float acc[SPB1];
        #pragma unroll
        for (int s = 0; s < SPB1; ++s) acc[s] = b0[t];
        #pragma unroll 8
        for (int i = 0; i < 32; ++i) {
            float w = W0[i * 256 + t];
            #pragma unroll
            for (int s = 0; s < SPB1; ++s) acc[s] += Zt[s][i] * w;
        }
        #pragma unroll
        for (int s = 0; s < SPB1; ++s) {
            float h, sp, fpp;
            silu_derivs(acc[s], h, sp, fpp);
            Ha[t][s] = h;
            S[(0 * BS + m0 + s) * HID + t] = sp;
            f2a[0][s] = fpp;
        }
    }
    __syncthreads();
    fwd_layer(1, t, m0, Ha, Hb, W1, b1, f2a[1], S);  // h2
    __syncthreads();
    fwd_layer(2, t, m0, Hb, Ha, W2, b2, f2a[2], S);  // h3
    __syncthreads();
    // ---- layer 4 + start of backward ----
    {
        float acc[SPB1];
        #pragma unroll
        for (int s = 0; s < SPB1; ++s) acc[s] = b3[t];
        const float4* H4 = (const float4*)&Ha[0][0];
        #pragma unroll 4
        for (int i = 0; i < 256; ++i) {
            float w = W3[i * 256 + t];
            float4 h0 = H4[i * 2 + 0];
            float4 h1 = H4[i * 2 + 1];
            acc[0] += h0.x * w; acc[1] += h0.y * w; acc[2] += h0.z * w; acc[3] += h0.w * w;
            acc[4] += h1.x * w; acc[5] += h1.y * w; acc[6] += h1.z * w; acc[7] += h1.w * w;
        }
        float w4 = W4[t];
        #pragma unroll
        for (int s = 0; s < SPB1; ++s) {
            float h, sp, fpp;
            silu_derivs(acc[s], h, sp, fpp);
            Hb[t][s] = w4 * sp;                          // delta_a4
            C[(3 * BS + m0 + s) * HID + t] = w4 * fpp;   // c4
        }
    }
    __syncthreads();
    bwd_layer(2, t, m0, Hb, Ha, WT3, f2a[2], S, C);  // delta_a3 in Ha
    __syncthreads();
    bwd_layer(1, t, m0, Ha, Hb, WT2, f2a[1], S, C);  // delta_a2 in Hb
    __syncthreads();
    bwd_layer(0, t, m0, Hb, Ha, WT1, f2a[0], S, C);  // delta_a1 in Ha
    __syncthreads();
    // ---- gradient: g[k] = sum_i W0[k][i] * delta_a1[i] ----
    {
        const int k = t & 31, sh = t >> 5;
        float acc = 0.0f;
        #pragma unroll 4
        for (int i = 0; i < 256; ++i) acc += WT0[i * 32 + k] * Ha[i][sh];
        if (k < 16) G[(m0 + sh) * 16 + k] = acc;
    }
}

// ---------------- kernel 2: 32x32 MFMA tangent propagation + Hessian + solve ----
// 1 sample/block, 4 waves; wave w owns output cols 64w..64w+63.
// T (fp32) lives in LDS; epilogue parallel across waves; C/S prefetched 1 phase ahead.
#define RS2 72     // shorts per row (144 B)
#define TFPAD 260  // floats per Tf row

__global__ __launch_bounds__(256, 2) void k_stage2(
    const float* __restrict__ z,
    const float* __restrict__ W0,
    const ushort* __restrict__ WBT,
    const float* __restrict__ S, const float* __restrict__ C, const float* __restrict__ G,
    float* __restrict__ out)
{
    // slots: 0=ASh 1=ASl 2=ACh 3=ACl 4=TPh 5=TPl  (each 32 x RS2 shorts)
    __shared__ __align__(16) ushort SMEM[6 * 32 * RS2];   // 27648 B
    __shared__ __align__(16) float Tf[32 * TFPAD];        // 33280 B
    __shared__ float HCl[32][16];
    __shared__ float Msys[16][17];
    __shared__ float vvs[16];

    const int t    = threadIdx.x;
    const int m    = blockIdx.x;
    const int lane = t & 63;
    const int w    = t >> 6;       // wave 0..3
    const int ln   = lane & 31;
    const int hf   = lane >> 5;
    const int er   = t >> 3;          // epilogue row 0..31
    const int ej   = (t & 7) * 8;     // epilogue col offset 0,8,..56

#define SLOT(a) (&SMEM[(a) * 32 * RS2])

    f32x16 Tnxt[2];
    f32x16 Dacc;
    #pragma unroll
    for (int r = 0; r < 16; ++r) { Tnxt[0][r] = 0.0f; Tnxt[1][r] = 0.0f; Dacc[r] = 0.0f; }

    // init Tf = T1 = W0  (all four column quarters)
    #pragma unroll
    for (int q = 0; q < 4; ++q) {
        const int c = q * 64 + ej;
        float4 a = *(const float4*)&W0[er * HID + c];
        float4 b = *(const float4*)&W0[er * HID + c + 4];
        *(float4*)&Tf[er * TFPAD + c]     = a;
        *(float4*)&Tf[er * TFPAD + c + 4] = b;
    }
    __syncthreads();

    // prefetch C/S for (lay=0, p=0)
    float4 cc0, cc1, ss0, ss1;
    {
        const float* Cp = &C[(0 * BS + m) * HID + ej];
        const float* Sp = &S[(0 * BS + m) * HID + ej];
        cc0 = *(const float4*)Cp; cc1 = *(const float4*)(Cp + 4);
        ss0 = *(const float4*)Sp; ss1 = *(const float4*)(Sp + 4);
    }

    for (int lay = 0; lay < 4; ++lay) {
        for (int p = 0; p < 4; ++p) {
            // ---- issue next-phase C/S loads (consumed next phase; barrier drains them)
            float4 cn0, cn1, sn0, sn1;
            const int nlay = (p < 3) ? lay : lay + 1;
            const int np   = (p < 3) ? p + 1 : 0;
            if (nlay < 4) {
                const float* Cp = &C[(nlay * BS + m) * HID + np * 64 + ej];
                cn0 = *(const float4*)Cp; cn1 = *(const float4*)(Cp + 4);
                if (nlay < 3) {
                    const float* Sp = &S[(nlay * BS + m) * HID + np * 64 + ej];
                    sn0 = *(const float4*)Sp; sn1 = *(const float4*)(Sp + 4);
                }
            }

            // ---------- epilogue: all 256 threads split-scale phase-p cols ----------
            {
                const int cg = p * 64 + ej;
                float tv[8], tmp[8];
                *(float4*)&tv[0] = *(const float4*)&Tf[er * TFPAD + cg];
                *(float4*)&tv[4] = *(const float4*)&Tf[er * TFPAD + cg + 4];
                uint4 H, L;
                tmp[0] = cc0.x * tv[0]; tmp[1] = cc0.y * tv[1];
                tmp[2] = cc0.z * tv[2]; tmp[3] = cc0.w * tv[3];
                tmp[4] = cc1.x * tv[4]; tmp[5] = cc1.y * tv[5];
                tmp[6] = cc1.z * tv[6]; tmp[7] = cc1.w * tv[7];
                split8v(tmp, H, L);
                *(uint4*)(SLOT(2) + er * RS2 + ej) = H;
                *(uint4*)(SLOT(3) + er * RS2 + ej) = L;
                if (lay < 3) {
                    tmp[0] = ss0.x * tv[0]; tmp[1] = ss0.y * tv[1];
                    tmp[2] = ss0.z * tv[2]; tmp[3] = ss0.w * tv[3];
                    tmp[4] = ss1.x * tv[4]; tmp[5] = ss1.y * tv[5];
                    tmp[6] = ss1.z * tv[6]; tmp[7] = ss1.w * tv[7];
                    split8v(tmp, H, L);
                    *(uint4*)(SLOT(0) + er * RS2 + ej) = H;
                    *(uint4*)(SLOT(1) + er * RS2 + ej) = L;
                }
                if (er >= 16) {   // waves 2,3 — wave-uniform branch
                    split8v(tv, H, L);
                    *(uint4*)(SLOT(4) + (er - 16) * RS2 + ej) = H;
                    *(uint4*)(SLOT(5) + (er - 16) * RS2 + ej) = L;
                }
            }
            __syncthreads();

            // ---------- contraction: HC += (c.T) x Tp^T, wave w takes K-chunk w ----
            {
                const int ko = w * 16 + hf * 8;
                bf16x8 Bh = *(const bf16x8*)(SLOT(4) + ln * RS2 + ko);
                bf16x8 Bl = *(const bf16x8*)(SLOT(5) + ln * RS2 + ko);
                bf16x8 Ah = *(const bf16x8*)(SLOT(2) + ln * RS2 + ko);
                bf16x8 Al = *(const bf16x8*)(SLOT(3) + ln * RS2 + ko);
                Dacc = MFMA32(Ah, Bh, MFMA32(Al, Bh, MFMA32(Ah, Bl, Dacc)));
            }

            // ---------- GEMM: Tnxt += (s.T) @ W_{lay+1} over this phase's K --------
            if (lay < 3) {
                const ushort* WH = WBT + (lay * 2 + 0) * 65536;
                const ushort* WL = WBT + (lay * 2 + 1) * 65536;
                #pragma unroll
                for (int ks = 0; ks < 4; ++ks) {
                    const int ko = ks * 16 + hf * 8;
                    bf16x8 Ah = *(const bf16x8*)(SLOT(0) + ln * RS2 + ko);
                    bf16x8 Al = *(const bf16x8*)(SLOT(1) + ln * RS2 + ko);
                    const int kg = p * 64 + ko;
                    #pragma unroll
                    for (int nt = 0; nt < 2; ++nt) {
                        const int nr = w * 64 + nt * 32 + ln;
                        bf16x8 Bh = *(const bf16x8*)&WH[nr * 256 + kg];
                        bf16x8 Bl = *(const bf16x8*)&WL[nr * 256 + kg];
                        Tnxt[nt] = MFMA32(Ah, Bh,
                                   MFMA32(Al, Bh,
                                   MFMA32(Ah, Bl, Tnxt[nt])));
                    }
                }
            }
            __syncthreads();

            // ---- rotate prefetched C/S ----
            if (nlay < 4) {
                cc0 = cn0; cc1 = cn1;
                if (nlay < 3) { ss0 = sn0; ss1 = sn1; }
            }
        } // p

        // ---------- layer end: Tf <- Tnxt, reset ----------
        if (lay < 3) {
            #pragma unroll
            for (int nt = 0; nt < 2; ++nt) {
                const int col = w * 64 + nt * 32 + ln;
                #pragma unroll
                for (int r = 0; r < 16; ++r) {
                    const int row = (r & 3) + 8 * (r >> 2) + 4 * hf;
                    Tf[row * TFPAD + col] = Tnxt[nt][r];
                    Tnxt[nt][r] = 0.0f;
                }
            }
            __syncthreads();
        }
    } // lay

    // ---------- reduce Hessian partials across waves (overlay on SMEM) ----------
    float* Dred = (float*)SMEM;   // 4*16*64*4 = 16 KB <= 27.6 KB
    #pragma unroll
    for (int r = 0; r < 16; ++r)
        Dred[(w * 16 + r) * 64 + lane] = Dacc[r];
    __syncthreads();

    // ---------- wave-0 solve ----------
    if (w == 0) {
        #pragma unroll
        for (int r = 0; r < 16; ++r) {
            float v = Dred[r * 64 + lane] + Dred[(16 + r) * 64 + lane]
                    + Dred[(32 + r) * 64 + lane] + Dred[(48 + r) * 64 + lane];
            const int row = (r & 3) + 8 * (r >> 2) + 4 * hf;
            if (ln < 16) HCl[row][ln] = v;   // HC[k][j] = H[k][16+j]
        }

        float* M = &Msys[0][0];   // [16][17]
        float vr = 0.0f;
        if (lane < 16) {
            vr = z[m * 32 + 16 + lane];
            vvs[lane] = vr;
        }
        if (lane < 16) {
            #pragma unroll
            for (int j = 0; j < 16; ++j)
                M[lane * 17 + j] = HCl[16 + lane][j] + (lane == j ? 0.2f : 0.0f);
            float r = G[m * 16 + lane];
            #pragma unroll
            for (int j = 0; j < 16; ++j)
                r -= HCl[j][lane] * vvs[j];
            M[lane * 17 + 16] = r;
        }
        // Gauss-Jordan with partial pivoting (wave-synchronous)
        for (int k2 = 0; k2 < 16; ++k2) {
            float val = (lane < 16 && lane >= k2) ? fabsf(M[lane * 17 + k2]) : -1.0f;
            int idx = lane;
            #pragma unroll
            for (int off = 8; off > 0; off >>= 1) {
                float ov = __shfl_xor(val, off, 64);
                int oi = __shfl_xor(idx, off, 64);
                if (ov > val) { val = ov; idx = oi; }
            }
            const int p2 = __shfl(idx, 0, 64);
            if (p2 != k2 && lane < 17) {
                float tmp = M[k2 * 17 + lane];
                M[k2 * 17 + lane] = M[p2 * 17 + lane];
                M[p2 * 17 + lane] = tmp;
            }
            if (lane < 16) {
                const float f = (lane == k2) ? 0.0f : M[lane * 17 + k2] / M[k2 * 17 + k2];
                #pragma unroll
                for (int j = 0; j < 17; ++j)
                    M[lane * 17 + j] -= f * M[k2 * 17 + j];
            }
        }
        if (lane < 16) {
            out[m * 32 + lane]      = vr;
            out[m * 32 + 16 + lane] = M[lane * 17 + 16] / M[lane * 17 + lane];
        }
    }
#undef SLOT
}

extern "C" void kernel_launch(void* const* d_in, const int* in_sizes, int n_in,
                              void* d_out, int out_size, void* d_ws, size_t ws_size,
                              hipStream_t stream) {
    const float* z  = (const float*)d_in[1];
    const float* W0 = (const float*)d_in[2];
    const float* b0 = (const float*)d_in[3];
    const float* W1 = (const float*)d_in[4];
    const float* b1 = (const float*)d_in[5];
    const float* W2 = (const float*)d_in[6];
    const float* b2 = (const float*)d_in[7];
    const float* W3 = (const float*)d_in[8];
    const float* b3 = (const float*)d_in[9];
    const float* W4 = (const float*)d_in[10];
    float* out = (float*)d_out;
    float* ws  = (float*)d_ws;

    float* WT1 = ws + WT1_OFF;
    float* WT2 = ws + WT2_OFF;
    float* WT3 = ws + WT3_OFF;
    float* WT0 = ws + WT0_OFF;
    float* S   = ws + S_OFF;
    float* C   = ws + C_OFF;
    float* G   = ws + G_OFF;
    const ushort* WBT = (const ushort*)(ws + WBT_OFF);

    k_transpose<<<dim3(256, 4), 256, 0, stream>>>(W0, W1, W2, W3, ws);
    k_stage1<<<BS / SPB1, 256, 0, stream>>>(z, W0, b0, W1, b1, W2, b2, W3, b3, W4,
                                            WT0, WT1, WT2, WT3, S, C, G);
    k_stage2<<<BS, 256, 0, stream>>>(z, W0, WBT, S, C, G, out);
}

// Round 7
// 1203.931 us; speedup vs baseline: 2.9819x; 1.0549x over previous
//
#include <hip/hip_runtime.h>
#include <hip/hip_bf16.h>
#include <math.h>

#define BS 8192
#define HID 256
#define SPB1 8

// ---- workspace layout (float element offsets) ----
#define WT1_OFF 0
#define WT2_OFF 65536
#define WT3_OFF 131072
#define WT0_OFF 196608
#define S_OFF   204800
#define C_OFF   (S_OFF + 4 * BS * HID)
#define G_OFF   (C_OFF + 4 * BS * HID)
#define WBT_OFF (G_OFF + BS * 16)
// WBT region: brick-swizzled W: 3 lay x 2 (hi,lo) x 8 nt x 16 kb x 64 lanes x 8 shorts
//           = 393216 shorts = 786432 B after WBT_OFF floats

typedef __attribute__((ext_vector_type(8))) short bf16x8;
typedef __attribute__((ext_vector_type(16))) float f32x16;
#define MFMA32(A, B, C) __builtin_amdgcn_mfma_f32_32x32x16_bf16(A, B, C, 0, 0, 0)

__device__ __forceinline__ ushort bf16_rne(float x) {
    unsigned u = __float_as_uint(x);
    unsigned r = u + 0x7FFFu + ((u >> 16) & 1u);
    return (ushort)(r >> 16);
}
__device__ __forceinline__ void bsplit(float x, ushort& hi, ushort& lo) {
    hi = bf16_rne(x);
    float hf = __uint_as_float(((unsigned)hi) << 16);
    lo = bf16_rne(x - hf);
}

// packed split via v_cvt_pk_bf16_f32 (gfx950): 2 elements -> hi uint, lo uint
__device__ __forceinline__ uint pk2(float a, float b) {
    __hip_bfloat162 h = __float22bfloat162_rn(float2{a, b});
    uint u; __builtin_memcpy(&u, &h, 4); return u;
}
__device__ __forceinline__ void split2(float a, float b, uint& hp, uint& lp) {
    hp = pk2(a, b);
    float ha = __uint_as_float(hp << 16);
    float hb = __uint_as_float(hp & 0xFFFF0000u);
    lp = pk2(a - ha, b - hb);
}
__device__ __forceinline__ void split8v(const float* v, uint4& H, uint4& L) {
    split2(v[0], v[1], H.x, L.x);
    split2(v[2], v[3], H.y, L.y);
    split2(v[4], v[5], H.z, L.z);
    split2(v[6], v[7], H.w, L.w);
}

__device__ __forceinline__ void silu_derivs(float a, float& h, float& sp, float& fpp) {
    float sig = 1.0f / (1.0f + __expf(-a));
    float om  = 1.0f - sig;
    h   = a * sig;
    sp  = sig * (1.0f + a * om);                       // silu'
    fpp = sig * om * (2.0f + a * (1.0f - 2.0f * sig)); // silu''
}

// ---------------- kernel 0: weight transposes + bf16 brick swizzle ----------------
// Brick layout: brick = (lay*2+hl)*128 + ntg*16 + kb ; element = brick*512 + lane*8 + j
//   where ntg = col>>5, ln = col&31, kb = k>>4, hfb = (k>>3)&1, lane = ln + 32*hfb, j = k&7.
// GEMM B-frag load becomes one coalesced 1 KB transaction per wave.
__global__ void k_transpose(const float* __restrict__ W0, const float* __restrict__ W1,
                            const float* __restrict__ W2, const float* __restrict__ W3,
                            float* __restrict__ ws) {
    float* WT1 = ws + WT1_OFF;
    float* WT2 = ws + WT2_OFF;
    float* WT3 = ws + WT3_OFF;
    float* WT0 = ws + WT0_OFF;
    ushort* WBT = (ushort*)(ws + WBT_OFF);
    int o = blockIdx.x;      // 0..255 (output col)
    int t = threadIdx.x;     // 0..255 (input row k)
    int which = blockIdx.y;  // 0..3
    if (which < 3) {
        const float* W = (which == 0) ? W1 : (which == 1) ? W2 : W3;
        float* WT = (which == 0) ? WT1 : (which == 1) ? WT2 : WT3;
        float v = W[t * 256 + o];
        WT[o * 256 + t] = v;
        ushort h, l;
        bsplit(v, h, l);
        const int ntg = o >> 5, ln0 = o & 31;
        const int kb = t >> 4, hfb = (t >> 3) & 1, j = t & 7;
        const int laneidx = ln0 + 32 * hfb;
        WBT[(((which * 2 + 0) * 128) + ntg * 16 + kb) * 512 + laneidx * 8 + j] = h;
        WBT[(((which * 2 + 1) * 128) + ntg * 16 + kb) * 512 + laneidx * 8 + j] = l;
    } else if (t < 32) {
        WT0[o * 32 + t] = W0[t * 256 + o]; // WT0[i][k] = W0[k][i]
    }
}

// ---------------- kernel 1: forward + backward (8 samples/block) ----------------
__device__ __forceinline__ void fwd_layer(int L, int t, int m0,
        const float (*Hin)[SPB1], float (*Hout)[SPB1],
        const float* __restrict__ W, const float* __restrict__ b,
        float* __restrict__ f2, float* __restrict__ S)
{
    float acc[SPB1];
    #pragma unroll
    for (int s = 0; s < SPB1; ++s) acc[s] = b[t];
    const float4* H4 = (const float4*)&Hin[0][0];
    #pragma unroll 4
    for (int i = 0; i < 256; ++i) {
        float w = W[i * 256 + t];
        float4 h0 = H4[i * 2 + 0];
        float4 h1 = H4[i * 2 + 1];
        acc[0] += h0.x * w; acc[1] += h0.y * w; acc[2] += h0.z * w; acc[3] += h0.w * w;
        acc[4] += h1.x * w; acc[5] += h1.y * w; acc[6] += h1.z * w; acc[7] += h1.w * w;
    }
    #pragma unroll
    for (int s = 0; s < SPB1; ++s) {
        float h, sp, fpp;
        silu_derivs(acc[s], h, sp, fpp);
        Hout[t][s] = h;
        S[(L * BS + m0 + s) * HID + t] = sp;
        f2[s] = fpp;
    }
}

__device__ __forceinline__ void bwd_layer(int L, int t, int m0,
        const float (*Din)[SPB1], float (*Dout)[SPB1],
        const float* __restrict__ WT,
        const float* __restrict__ f2,
        const float* __restrict__ S, float* __restrict__ C)
{
    float acc[SPB1];
    #pragma unroll
    for (int s = 0; s < SPB1; ++s) acc[s] = 0.0f;
    const float4* D4 = (const float4*)&Din[0][0];
    #pragma unroll 4
    for (int o = 0; o < 256; ++o) {
        float w = WT[o * 256 + t];
        float4 d0 = D4[o * 2 + 0];
        float4 d1 = D4[o * 2 + 1];
        acc[0] += d0.x * w; acc[1] += d0.y * w; acc[2] += d0.z * w; acc[3] += d0.w * w;
        acc[4] += d1.x * w; acc[5] += d1.y * w; acc[6] += d1.z * w; acc[7] += d1.w * w;
    }
    #pragma unroll
    for (int s = 0; s < SPB1; ++s) {
        float dh = acc[s];
        float sl = S[(L * BS + m0 + s) * HID + t];
        C[(L * BS + m0 + s) * HID + t] = dh * f2[s];
        Dout[t][s] = dh * sl;  // delta_a
    }
}

__global__ __launch_bounds__(256) void k_stage1(
    const float* __restrict__ z,
    const float* __restrict__ W0, const float* __restrict__ b0,
    const float* __restrict__ W1, const float* __restrict__ b1,
    const float* __restrict__ W2, const float* __restrict__ b2,
    const float* __restrict__ W3, const float* __restrict__ b3,
    const float* __restrict__ W4,
    const float* __restrict__ WT0, const float* __restrict__ WT1,
    const float* __restrict__ WT2, const float* __restrict__ WT3,
    float* __restrict__ S, float* __restrict__ C, float* __restrict__ G)
{
    __shared__ __align__(16) float Zt[SPB1][32];
    __shared__ __align__(16) float Ha[256][SPB1];
    __shared__ __align__(16) float Hb[256][SPB1];
    const int t  = threadIdx.x;
    const int m0 = blockIdx.x * SPB1;
    float f2a[3][SPB1];   // silu'' layers 0..2: same-thread produce/consume

    Zt[t >> 5][t & 31] = z[(m0 + (t >> 5)) * 32 + (t & 31)];
    __syncthreads();

    // ---- layer 1: a1 = z @ W0 + b0 ----
    {
        float acc[SPB1];
        #pragma unroll
        for (int s = 0; s < SPB1; ++s) acc[s] = b0[t];
        #pragma unroll 8
        for (int i = 0; i < 32; ++i) {
            float w = W0[i * 256 + t];
            #pragma unroll
            for (int s = 0; s < SPB1; ++s) acc[s] += Zt[s][i] * w;
        }
        #pragma unroll
        for (int s = 0; s < SPB1; ++s) {
            float h, sp, fpp;
            silu_derivs(acc[s], h, sp, fpp);
            Ha[t][s] = h;
            S[(0 * BS + m0 + s) * HID + t] = sp;
            f2a[0][s] = fpp;
        }
    }
    __syncthreads();
    fwd_layer(1, t, m0, Ha, Hb, W1, b1, f2a[1], S);  // h2
    __syncthreads();
    fwd_layer(2, t, m0, Hb, Ha, W2, b2, f2a[2], S);  // h3
    __syncthreads();
    // ---- layer 4 + start of backward ----
    {
        float acc[SPB1];
        #pragma unroll
        for (int s = 0; s < SPB1; ++s) acc[s] = b3[t];
        const float4* H4 = (const float4*)&Ha[0][0];
        #pragma unroll 4
        for (int i = 0; i < 256; ++i) {
            float w = W3[i * 256 + t];
            float4 h0 = H4[i * 2 + 0];
            float4 h1 = H4[i * 2 + 1];
            acc[0] += h0.x * w; acc[1] += h0.y * w; acc[2] += h0.z * w; acc[3] += h0.w * w;
            acc[4] += h1.x * w; acc[5] += h1.y * w; acc[6] += h1.z * w; acc[7] += h1.w * w;
        }
        float w4 = W4[t];
        #pragma unroll
        for (int s = 0; s < SPB1; ++s) {
            float h, sp, fpp;
            silu_derivs(acc[s], h, sp, fpp);
            Hb[t][s] = w4 * sp;                          // delta_a4
            C[(3 * BS + m0 + s) * HID + t] = w4 * fpp;   // c4
        }
    }
    __syncthreads();
    bwd_layer(2, t, m0, Hb, Ha, WT3, f2a[2], S, C);  // delta_a3 in Ha
    __syncthreads();
    bwd_layer(1, t, m0, Ha, Hb, WT2, f2a[1], S, C);  // delta_a2 in Hb
    __syncthreads();
    bwd_layer(0, t, m0, Hb, Ha, WT1, f2a[0], S, C);  // delta_a1 in Ha
    __syncthreads();
    // ---- gradient: g[k] = sum_i W0[k][i] * delta_a1[i] ----
    {
        const int k = t & 31, sh = t >> 5;
        float acc = 0.0f;
        #pragma unroll 4
        for (int i = 0; i < 256; ++i) acc += WT0[i * 32 + k] * Ha[i][sh];
        if (k < 16) G[(m0 + sh) * 16 + k] = acc;
    }
}

// ---------------- kernel 2: 32x32 MFMA tangent propagation + Hessian + solve ----
// 1 sample/block, 4 waves; wave w owns output cols 64w..64w+63.
// T (fp32) in LDS; epilogue parallel across waves; C/S prefetched 1 phase ahead;
// W read via coalesced fragment bricks (1 KB/wave/load).
#define RS2 72     // shorts per row (144 B)
#define TFPAD 260  // floats per Tf row

__global__ __launch_bounds__(256, 2) void k_stage2(
    const float* __restrict__ z,
    const float* __restrict__ W0,
    const ushort* __restrict__ WBT,
    const float* __restrict__ S, const float* __restrict__ C, const float* __restrict__ G,
    float* __restrict__ out)
{
    // slots: 0=ASh 1=ASl 2=ACh 3=ACl 4=TPh 5=TPl  (each 32 x RS2 shorts)
    __shared__ __align__(16) ushort SMEM[6 * 32 * RS2];   // 27648 B
    __shared__ __align__(16) float Tf[32 * TFPAD];        // 33280 B
    __shared__ float HCl[32][16];
    __shared__ float Msys[16][17];
    __shared__ float vvs[16];

    const int t    = threadIdx.x;
    const int m    = blockIdx.x;
    const int lane = t & 63;
    const int w    = t >> 6;       // wave 0..3
    const int ln   = lane & 31;
    const int hf   = lane >> 5;
    const int er   = t >> 3;          // epilogue row 0..31
    const int ej   = (t & 7) * 8;     // epilogue col offset 0,8,..56

#define SLOT(a) (&SMEM[(a) * 32 * RS2])

    f32x16 Tnxt[2];
    f32x16 Dacc;
    #pragma unroll
    for (int r = 0; r < 16; ++r) { Tnxt[0][r] = 0.0f; Tnxt[1][r] = 0.0f; Dacc[r] = 0.0f; }

    // init Tf = T1 = W0  (all four column quarters)
    #pragma unroll
    for (int q = 0; q < 4; ++q) {
        const int c = q * 64 + ej;
        float4 a = *(const float4*)&W0[er * HID + c];
        float4 b = *(const float4*)&W0[er * HID + c + 4];
        *(float4*)&Tf[er * TFPAD + c]     = a;
        *(float4*)&Tf[er * TFPAD + c + 4] = b;
    }
    __syncthreads();

    // prefetch C/S for (lay=0, p=0)
    float4 cc0, cc1, ss0, ss1;
    {
        const float* Cp = &C[(0 * BS + m) * HID + ej];
        const float* Sp = &S[(0 * BS + m) * HID + ej];
        cc0 = *(const float4*)Cp; cc1 = *(const float4*)(Cp + 4);
        ss0 = *(const float4*)Sp; ss1 = *(const float4*)(Sp + 4);
    }

    for (int lay = 0; lay < 4; ++lay) {
        for (int p = 0; p < 4; ++p) {
            // ---- issue next-phase C/S loads (consumed next phase; barrier drains them)
            float4 cn0, cn1, sn0, sn1;
            const int nlay = (p < 3) ? lay : lay + 1;
            const int np   = (p < 3) ? p + 1 : 0;
            if (nlay < 4) {
                const float* Cp = &C[(nlay * BS + m) * HID + np * 64 + ej];
                cn0 = *(const float4*)Cp; cn1 = *(const float4*)(Cp + 4);
                if (nlay < 3) {
                    const float* Sp = &S[(nlay * BS + m) * HID + np * 64 + ej];
                    sn0 = *(const float4*)Sp; sn1 = *(const float4*)(Sp + 4);
                }
            }

            // ---------- epilogue: all 256 threads split-scale phase-p cols ----------
            {
                const int cg = p * 64 + ej;
                float tv[8], tmp[8];
                *(float4*)&tv[0] = *(const float4*)&Tf[er * TFPAD + cg];
                *(float4*)&tv[4] = *(const float4*)&Tf[er * TFPAD + cg + 4];
                uint4 H, L;
                tmp[0] = cc0.x * tv[0]; tmp[1] = cc0.y * tv[1];
                tmp[2] = cc0.z * tv[2]; tmp[3] = cc0.w * tv[3];
                tmp[4] = cc1.x * tv[4]; tmp[5] = cc1.y * tv[5];
                tmp[6] = cc1.z * tv[6]; tmp[7] = cc1.w * tv[7];
                split8v(tmp, H, L);
                *(uint4*)(SLOT(2) + er * RS2 + ej) = H;
                *(uint4*)(SLOT(3) + er * RS2 + ej) = L;
                if (lay < 3) {
                    tmp[0] = ss0.x * tv[0]; tmp[1] = ss0.y * tv[1];
                    tmp[2] = ss0.z * tv[2]; tmp[3] = ss0.w * tv[3];
                    tmp[4] = ss1.x * tv[4]; tmp[5] = ss1.y * tv[5];
                    tmp[6] = ss1.z * tv[6]; tmp[7] = ss1.w * tv[7];
                    split8v(tmp, H, L);
                    *(uint4*)(SLOT(0) + er * RS2 + ej) = H;
                    *(uint4*)(SLOT(1) + er * RS2 + ej) = L;
                }
                if (er >= 16) {   // waves 2,3 — wave-uniform branch
                    split8v(tv, H, L);
                    *(uint4*)(SLOT(4) + (er - 16) * RS2 + ej) = H;
                    *(uint4*)(SLOT(5) + (er - 16) * RS2 + ej) = L;
                }
            }
            __syncthreads();

            // ---------- B-fragment brick prefetch (coalesced 1 KB/wave loads) -------
            bf16x8 Bh[4][2], Bl[4][2];
            if (lay < 3) {
                #pragma unroll
                for (int ks = 0; ks < 4; ++ks) {
                    const int kb = p * 4 + ks;
                    #pragma unroll
                    for (int nt = 0; nt < 2; ++nt) {
                        const int ntg = w * 2 + nt;
                        Bh[ks][nt] = *(const bf16x8*)&WBT[
                            (((lay * 2 + 0) * 128) + ntg * 16 + kb) * 512 + lane * 8];
                        Bl[ks][nt] = *(const bf16x8*)&WBT[
                            (((lay * 2 + 1) * 128) + ntg * 16 + kb) * 512 + lane * 8];
                    }
                }
            }

            // ---------- contraction: HC += (c.T) x Tp^T, wave w takes K-chunk w ----
            {
                const int ko = w * 16 + hf * 8;
                bf16x8 Bph = *(const bf16x8*)(SLOT(4) + ln * RS2 + ko);
                bf16x8 Bpl = *(const bf16x8*)(SLOT(5) + ln * RS2 + ko);
                bf16x8 Ah = *(const bf16x8*)(SLOT(2) + ln * RS2 + ko);
                bf16x8 Al = *(const bf16x8*)(SLOT(3) + ln * RS2 + ko);
                Dacc = MFMA32(Ah, Bph, MFMA32(Al, Bph, MFMA32(Ah, Bpl, Dacc)));
            }

            // ---------- GEMM: Tnxt += (s.T) @ W_{lay+1} over this phase's K --------
            if (lay < 3) {
                #pragma unroll
                for (int ks = 0; ks < 4; ++ks) {
                    const int ko = ks * 16 + hf * 8;
                    bf16x8 Ah = *(const bf16x8*)(SLOT(0) + ln * RS2 + ko);
                    bf16x8 Al = *(const bf16x8*)(SLOT(1) + ln * RS2 + ko);
                    #pragma unroll
                    for (int nt = 0; nt < 2; ++nt) {
                        Tnxt[nt] = MFMA32(Ah, Bh[ks][nt],
                                   MFMA32(Al, Bh[ks][nt],
                                   MFMA32(Ah, Bl[ks][nt], Tnxt[nt])));
                    }
                }
            }
            __syncthreads();

            // ---- rotate prefetched C/S ----
            if (nlay < 4) {
                cc0 = cn0; cc1 = cn1;
                if (nlay < 3) { ss0 = sn0; ss1 = sn1; }
            }
        } // p

        // ---------- layer end: Tf <- Tnxt, reset ----------
        if (lay < 3) {
            #pragma unroll
            for (int nt = 0; nt < 2; ++nt) {
                const int col = w * 64 + nt * 32 + ln;
                #pragma unroll
                for (int r = 0; r < 16; ++r) {
                    const int row = (r & 3) + 8 * (r >> 2) + 4 * hf;
                    Tf[row * TFPAD + col] = Tnxt[nt][r];
                    Tnxt[nt][r] = 0.0f;
                }
            }
            __syncthreads();
        }
    } // lay

    // ---------- reduce Hessian partials across waves (overlay on SMEM) ----------
    float* Dred = (float*)SMEM;   // 4*16*64*4 = 16 KB <= 27.6 KB
    #pragma unroll
    for (int r = 0; r < 16; ++r)
        Dred[(w * 16 + r) * 64 + lane] = Dacc[r];
    __syncthreads();

    // ---------- wave-0 solve ----------
    if (w == 0) {
        #pragma unroll
        for (int r = 0; r < 16; ++r) {
            float v = Dred[r * 64 + lane] + Dred[(16 + r) * 64 + lane]
                    + Dred[(32 + r) * 64 + lane] + Dred[(48 + r) * 64 + lane];
            const int row = (r & 3) + 8 * (r >> 2) + 4 * hf;
            if (ln < 16) HCl[row][ln] = v;   // HC[k][j] = H[k][16+j]
        }

        float* M = &Msys[0][0];   // [16][17]
        float vr = 0.0f;
        if (lane < 16) {
            vr = z[m * 32 + 16 + lane];
            vvs[lane] = vr;
        }
        if (lane < 16) {
            #pragma unroll
            for (int j = 0; j < 16; ++j)
                M[lane * 17 + j] = HCl[16 + lane][j] + (lane == j ? 0.2f : 0.0f);
            float r = G[m * 16 + lane];
            #pragma unroll
            for (int j = 0; j < 16; ++j)
                r -= HCl[j][lane] * vvs[j];
            M[lane * 17 + 16] = r;
        }
        // Gauss-Jordan with partial pivoting (wave-synchronous)
        for (int k2 = 0; k2 < 16; ++k2) {
            float val = (lane < 16 && lane >= k2) ? fabsf(M[lane * 17 + k2]) : -1.0f;
            int idx = lane;
            #pragma unroll
            for (int off = 8; off > 0; off >>= 1) {
                float ov = __shfl_xor(val, off, 64);
                int oi = __shfl_xor(idx, off, 64);
                if (ov > val) { val = ov; idx = oi; }
            }
            const int p2 = __shfl(idx, 0, 64);
            if (p2 != k2 && lane < 17) {
                float tmp = M[k2 * 17 + lane];
                M[k2 * 17 + lane] = M[p2 * 17 + lane];
                M[p2 * 17 + lane] = tmp;
            }
            if (lane < 16) {
                const float f = (lane == k2) ? 0.0f : M[lane * 17 + k2] / M[k2 * 17 + k2];
                #pragma unroll
                for (int j = 0; j < 17; ++j)
                    M[lane * 17 + j] -= f * M[k2 * 17 + j];
            }
        }
        if (lane < 16) {
            out[m * 32 + lane]      = vr;
            out[m * 32 + 16 + lane] = M[lane * 17 + 16] / M[lane * 17 + lane];
        }
    }
#undef SLOT
}

extern "C" void kernel_launch(void* const* d_in, const int* in_sizes, int n_in,
                              void* d_out, int out_size, void* d_ws, size_t ws_size,
                              hipStream_t stream) {
    const float* z  = (const float*)d_in[1];
    const float* W0 = (const float*)d_in[2];
    const float* b0 = (const float*)d_in[3];
    const float* W1 = (const float*)d_in[4];
    const float* b1 = (const float*)d_in[5];
    const float* W2 = (const float*)d_in[6];
    const float* b2 = (const float*)d_in[7];
    const float* W3 = (const float*)d_in[8];
    const float* b3 = (const float*)d_in[9];
    const float* W4 = (const float*)d_in[10];
    float* out = (float*)d_out;
    float* ws  = (float*)d_ws;

    float* WT1 = ws + WT1_OFF;
    float* WT2 = ws + WT2_OFF;
    float* WT3 = ws + WT3_OFF;
    float* WT0 = ws + WT0_OFF;
    float* S   = ws + S_OFF;
    float* C   = ws + C_OFF;
    float* G   = ws + G_OFF;
    const ushort* WBT = (const ushort*)(ws + WBT_OFF);

    k_transpose<<<dim3(256, 4), 256, 0, stream>>>(W0, W1, W2, W3, ws);
    k_stage1<<<BS / SPB1, 256, 0, stream>>>(z, W0, b0, W1, b1, W2, b2, W3, b3, W4,
                                            WT0, WT1, WT2, WT3, S, C, G);
    k_stage2<<<BS, 256, 0, stream>>>(z, W0, WBT, S, C, G, out);
}